// Round 1
// baseline (1913.443 us; speedup 1.0000x reference)
//
#include <hip/hip_runtime.h>
#include <cstdint>
#include <cstddef>

typedef unsigned short u16;
typedef __attribute__((ext_vector_type(8))) short s8v;   // 8 x bf16 (4 VGPRs) MFMA A/B frag
typedef __attribute__((ext_vector_type(4))) float f4v;   // MFMA C/D frag

__device__ __forceinline__ float bf2f(u16 u) {
  union { unsigned u; float f; } v; v.u = ((unsigned)u) << 16; return v.f;
}
__device__ __forceinline__ u16 f2bf(float f) {
  union { float f; unsigned u; } v; v.f = f;
  unsigned r = v.u + 0x7FFFu + ((v.u >> 16) & 1u);   // RNE
  return (u16)(r >> 16);
}

// async global->LDS, 16B per lane. LDS dest must be wave-uniform base; HW adds lane*16.
__device__ __forceinline__ void async16(u16* lds, const u16* g) {
  __builtin_amdgcn_global_load_lds((const __attribute__((address_space(1))) void*)g,
                                   (__attribute__((address_space(3))) void*)lds,
                                   16, 0, 0);
}

// ---------------- elementwise f32 -> bf16 ----------------
__global__ __launch_bounds__(256) void k_f32_to_bf16(const float* __restrict__ in,
                                                     u16* __restrict__ out, int n8) {
  int i = blockIdx.x * 256 + threadIdx.x;
  if (i >= n8) return;
  const float4* p = (const float4*)(in + (size_t)i * 8);
  float4 a = p[0], b = p[1];
  s8v ov;
  ov[0] = (short)f2bf(a.x); ov[1] = (short)f2bf(a.y);
  ov[2] = (short)f2bf(a.z); ov[3] = (short)f2bf(a.w);
  ov[4] = (short)f2bf(b.x); ov[5] = (short)f2bf(b.y);
  ov[6] = (short)f2bf(b.z); ov[7] = (short)f2bf(b.w);
  *(s8v*)(out + (size_t)i * 8) = ov;
}

// ---------------- W (K,N) f32 -> Wt (N,K) bf16 ----------------
__global__ __launch_bounds__(256) void k_transpose_bf16(const float* __restrict__ W,
                                                        u16* __restrict__ Wt, int K, int N) {
  __shared__ float tile[32][33];
  int n0 = blockIdx.x * 32, k0 = blockIdx.y * 32;
  int tx = threadIdx.x & 31, ty = threadIdx.x >> 5;  // ty 0..7
#pragma unroll
  for (int i = 0; i < 32; i += 8)
    tile[ty + i][tx] = W[(size_t)(k0 + ty + i) * N + n0 + tx];
  __syncthreads();
#pragma unroll
  for (int i = 0; i < 32; i += 8)
    Wt[(size_t)(n0 + ty + i) * K + k0 + tx] = f2bf(tile[tx][ty + i]);
}

// ---------------- GEMM: C(M,N) = A(M,K) * Bt(N,K)^T, bf16 in, bf16/f32 out ----------
// m97 structure: 128-wide tiles, BK=32, global_load_lds staging, 16x16x32 bf16 MFMA.
// REMAP: dest col = (col>>7)*192 + (col&127)  (pack head-128 into head-192 slots)
template <int BM, int BN, int WVM, int WVN, typename OutT, bool REMAP>
__global__ __launch_bounds__(256, 2) void k_gemm_bt(const u16* __restrict__ A,
                                                    const u16* __restrict__ Bt,
                                                    OutT* __restrict__ C,
                                                    int M, int N, int K, int ldc) {
  constexpr int FM = BM / WVM / 16, FN = BN / WVN / 16;
  __shared__ __align__(16) u16 As[BM * 32];
  __shared__ __align__(16) u16 Bs[BN * 32];
  const int tid = threadIdx.x, wv = tid >> 6, ln = tid & 63;
  const int lo = ln & 15, hi = ln >> 4;
  const int wr = wv / WVN, wc = wv % WVN;

  int nwg = gridDim.x, bid = blockIdx.x;
  int s = (bid & 7) * (nwg >> 3) + (bid >> 3);  // XCD swizzle (nwg % 8 == 0 for all uses)
  int gm = M / BM;
  int m0 = (s % gm) * BM, n0 = (s / gm) * BN;

  f4v acc[FM][FN] = {};

  for (int k0 = 0; k0 < K; k0 += 32) {
    __syncthreads();  // protect LDS from previous iteration's readers
#pragma unroll
    for (int i = 0; i < BM / 64; i++) {
      int r = i * 64 + wv * 16 + (ln >> 2);
      async16(&As[(i * 64 + wv * 16) * 32],
              A + (size_t)(m0 + r) * K + k0 + (ln & 3) * 8);
    }
#pragma unroll
    for (int i = 0; i < BN / 64; i++) {
      int r = i * 64 + wv * 16 + (ln >> 2);
      async16(&Bs[(i * 64 + wv * 16) * 32],
              Bt + (size_t)(n0 + r) * K + k0 + (ln & 3) * 8);
    }
    __syncthreads();  // drains vmcnt(0): staged data visible

    s8v af[FM], bf[FN];
#pragma unroll
    for (int m = 0; m < FM; m++)
      af[m] = *(const s8v*)&As[(wr * FM * 16 + m * 16 + lo) * 32 + hi * 8];
#pragma unroll
    for (int n = 0; n < FN; n++)
      bf[n] = *(const s8v*)&Bs[(wc * FN * 16 + n * 16 + lo) * 32 + hi * 8];
#pragma unroll
    for (int m = 0; m < FM; m++)
#pragma unroll
      for (int n = 0; n < FN; n++)
        acc[m][n] = __builtin_amdgcn_mfma_f32_16x16x32_bf16(af[m], bf[n], acc[m][n], 0, 0, 0);
  }

#pragma unroll
  for (int m = 0; m < FM; m++)
#pragma unroll
    for (int n = 0; n < FN; n++)
#pragma unroll
      for (int j = 0; j < 4; j++) {
        int row = m0 + wr * FM * 16 + m * 16 + hi * 4 + j;
        int col = n0 + wc * FN * 16 + n * 16 + lo;
        int dc = REMAP ? ((col >> 7) * 192 + (col & 127)) : col;
        float v = acc[m][n][j];
        if constexpr (sizeof(OutT) == 2)
          C[(size_t)row * ldc + dc] = (OutT)f2bf(v);
        else
          C[(size_t)row * ldc + dc] = (OutT)v;
      }
}

// ---------------- in-place RMSNorm over rows of bf16 (C <= 2048) ----------------
__global__ __launch_bounds__(256) void k_rmsnorm(u16* __restrict__ buf,
                                                 const float* __restrict__ g, int C) {
  int row = blockIdx.x;
  u16* p = buf + (size_t)row * C;
  int tid = threadIdx.x;
  bool act = tid * 8 < C;
  float x[8];
  float ss = 0.f;
  if (act) {
    s8v v = *(const s8v*)(p + tid * 8);
#pragma unroll
    for (int i = 0; i < 8; i++) { float xi = bf2f((u16)v[i]); x[i] = xi; ss += xi * xi; }
  }
#pragma unroll
  for (int off = 1; off < 64; off <<= 1) ss += __shfl_xor(ss, off);
  __shared__ float red[4];
  if ((tid & 63) == 0) red[tid >> 6] = ss;
  __syncthreads();
  float sc = rsqrtf((red[0] + red[1] + red[2] + red[3]) / (float)C + 1e-6f);
  if (act) {
    s8v ov;
#pragma unroll
    for (int i = 0; i < 8; i++) ov[i] = (short)f2bf(x[i] * sc * g[tid * 8 + i]);
    *(s8v*)(p + tid * 8) = ov;
  }
}

// ---------------- RoPE on q_rope, scatter into qbuf[:, h*192+128 ..] ----------------
__global__ __launch_bounds__(256) void k_rope_q(const u16* __restrict__ qr,
                                                const float* __restrict__ freqs,
                                                u16* __restrict__ qbuf) {
  int idx = blockIdx.x * 256 + threadIdx.x;  // (r,h)
  int r = idx >> 4, h = idx & 15;
  int t = r & 2047;
  const u16* src = qr + (size_t)r * 1024 + h * 64;
  u16* dst = qbuf + (size_t)r * 3072 + h * 192 + 128;
  const float* fc = freqs + (size_t)t * 64;
  u16 in[64], out[64];
#pragma unroll
  for (int c = 0; c < 8; c++) {
    s8v vv = *(const s8v*)(src + c * 8);
#pragma unroll
    for (int e = 0; e < 8; e++) in[c * 8 + e] = (u16)vv[e];
  }
#pragma unroll
  for (int i = 0; i < 32; i++) {
    float x1 = bf2f(in[2 * i]), x2 = bf2f(in[2 * i + 1]);
    float co = fc[2 * i], si = fc[2 * i + 1];
    out[2 * i] = f2bf(x1 * co - x2 * si);
    out[2 * i + 1] = f2bf(x1 * si + x2 * co);
  }
#pragma unroll
  for (int c = 0; c < 8; c++) {
    s8v ov;
#pragma unroll
    for (int e = 0; e < 8; e++) ov[e] = (short)out[c * 8 + e];
    *(s8v*)(dst + c * 8) = ov;
  }
}

// ---------------- RoPE on k_rope (shared across heads), broadcast into kbuf ----------
__global__ __launch_bounds__(256) void k_rope_k(const u16* __restrict__ kr,
                                                const float* __restrict__ freqs,
                                                u16* __restrict__ kbuf) {
  int idx = blockIdx.x * 256 + threadIdx.x;  // (r,h)
  int r = idx >> 4, h = idx & 15;
  int t = r & 2047;
  const u16* src = kr + (size_t)r * 64;
  u16* dst = kbuf + (size_t)r * 3072 + h * 192 + 128;
  const float* fc = freqs + (size_t)t * 64;
  u16 in[64], out[64];
#pragma unroll
  for (int c = 0; c < 8; c++) {
    s8v vv = *(const s8v*)(src + c * 8);
#pragma unroll
    for (int e = 0; e < 8; e++) in[c * 8 + e] = (u16)vv[e];
  }
#pragma unroll
  for (int i = 0; i < 32; i++) {
    float x1 = bf2f(in[2 * i]), x2 = bf2f(in[2 * i + 1]);
    float co = fc[2 * i], si = fc[2 * i + 1];
    out[2 * i] = f2bf(x1 * co - x2 * si);
    out[2 * i + 1] = f2bf(x1 * si + x2 * co);
  }
#pragma unroll
  for (int c = 0; c < 8; c++) {
    s8v ov;
#pragma unroll
    for (int e = 0; e < 8; e++) ov[e] = (short)out[c * 8 + e];
    *(s8v*)(dst + c * 8) = ov;
  }
}

// ---------------- V (token, h*128+d) -> Vt (B,H,128,T) ----------------
__global__ __launch_bounds__(256) void k_transpose_v(const u16* __restrict__ vtmp,
                                                     u16* __restrict__ vt) {
  __shared__ __align__(16) u16 tile[64][72];
  int r0 = blockIdx.x * 64, c0 = blockIdx.y * 64;
  int b = r0 >> 11, t0 = r0 & 2047;
  int h = c0 >> 7, d0 = c0 & 127;
  int tid = threadIdx.x;
  int ci = (tid & 7) * 8, ri = tid >> 3;  // ri 0..31
#pragma unroll
  for (int i = 0; i < 2; i++)
    *(s8v*)&tile[ri + 32 * i][ci] =
        *(const s8v*)(vtmp + (size_t)(r0 + ri + 32 * i) * 2048 + c0 + ci);
  __syncthreads();
  int tx = tid & 7, rr = tid >> 3;
#pragma unroll
  for (int i = 0; i < 2; i++) {
    int dr = rr + 32 * i;
    s8v ov;
#pragma unroll
    for (int e = 0; e < 8; e++) ov[e] = (short)tile[tx * 8 + e][dr];
    *(s8v*)(vt + (size_t)((b * 16 + h) * 128 + d0 + dr) * 2048 + t0 + tx * 8) = ov;
  }
}

// ---------------- causal flash attention ----------------
// Q,K: (B*T, H, 192) bf16 (nope|rope). V: (B,H,128,T) bf16. O: (B*T, H*128) bf16.
// Block = 4 waves; wave w owns q rows [qt*64 + w*16, +16); KV tiles of 64.
__global__ __launch_bounds__(256, 2) void k_attn(const u16* __restrict__ Q,
                                                 const u16* __restrict__ K,
                                                 const u16* __restrict__ V,
                                                 u16* __restrict__ O) {
  __shared__ __align__(16) u16 p_lds[4][16 * 88];  // stride 88: 16B-aligned, ~2-way banks
  int bid = blockIdx.x;
  int qt = bid & 31, h = (bid >> 5) & 15, b = bid >> 9;
  int tid = threadIdx.x, wv = tid >> 6, ln = tid & 63;
  int lo = ln & 15, hi = ln >> 4;
  int qb = qt * 64 + wv * 16;  // local q start (0..2032)

  const u16* qptr = Q + (size_t)(b * 2048 + qb + lo) * 3072 + h * 192 + hi * 8;
  s8v qf[6];
#pragma unroll
  for (int ks = 0; ks < 6; ks++) qf[ks] = *(const s8v*)(qptr + ks * 32);

  f4v Oa[8] = {};
  float m_r[4], l_r[4];
#pragma unroll
  for (int j = 0; j < 4; j++) { m_r[j] = -3e38f; l_r[j] = 0.f; }
  const float scale = 0.07216878364870323f;  // 1/sqrt(192)

  const u16* kbase = K + (size_t)(b * 2048) * 3072 + h * 192 + hi * 8;
  const u16* vbase = V + (size_t)((b * 16 + h) * 128) * 2048 + hi * 8;
  u16* pl = p_lds[wv];
  int last = (qb + 15) >> 6;

  for (int t = 0; t <= last; t++) {
    int kv0 = t * 64;
    f4v S[4] = {};
#pragma unroll
    for (int ks = 0; ks < 6; ks++)
#pragma unroll
      for (int nf = 0; nf < 4; nf++) {
        s8v kf = *(const s8v*)(kbase + (size_t)(kv0 + nf * 16 + lo) * 3072 + ks * 32);
        S[nf] = __builtin_amdgcn_mfma_f32_16x16x32_bf16(qf[ks], kf, S[nf], 0, 0, 0);
      }

    float p[4][4], tmax[4];
#pragma unroll
    for (int j = 0; j < 4; j++) tmax[j] = -3e38f;
    bool diag = (t == last);
#pragma unroll
    for (int nf = 0; nf < 4; nf++)
#pragma unroll
      for (int j = 0; j < 4; j++) {
        float sv = S[nf][j] * scale;
        if (diag && (kv0 + nf * 16 + lo > qb + hi * 4 + j)) sv = -3e38f;
        p[nf][j] = sv;
        tmax[j] = fmaxf(tmax[j], sv);
      }
#pragma unroll
    for (int off = 1; off < 16; off <<= 1)
#pragma unroll
      for (int j = 0; j < 4; j++) tmax[j] = fmaxf(tmax[j], __shfl_xor(tmax[j], off));
    float fj[4], ts[4];
#pragma unroll
    for (int j = 0; j < 4; j++) {
      float nm = fmaxf(m_r[j], tmax[j]);
      fj[j] = __expf(m_r[j] - nm);
      m_r[j] = nm;
      ts[j] = 0.f;
    }
#pragma unroll
    for (int nf = 0; nf < 4; nf++)
#pragma unroll
      for (int j = 0; j < 4; j++) {
        float pv = __expf(p[nf][j] - m_r[j]);
        p[nf][j] = pv;
        ts[j] += pv;
      }
#pragma unroll
    for (int off = 1; off < 16; off <<= 1)
#pragma unroll
      for (int j = 0; j < 4; j++) ts[j] += __shfl_xor(ts[j], off);
#pragma unroll
    for (int j = 0; j < 4; j++) l_r[j] = l_r[j] * fj[j] + ts[j];
#pragma unroll
    for (int df = 0; df < 8; df++)
#pragma unroll
      for (int j = 0; j < 4; j++) Oa[df][j] *= fj[j];

    // P (C-layout) -> LDS -> A-fragment layout
#pragma unroll
    for (int nf = 0; nf < 4; nf++)
#pragma unroll
      for (int j = 0; j < 4; j++)
        pl[(hi * 4 + j) * 88 + nf * 16 + lo] = f2bf(p[nf][j]);

#pragma unroll
    for (int ks2 = 0; ks2 < 2; ks2++) {
      s8v pa = *(const s8v*)&pl[lo * 88 + ks2 * 32 + hi * 8];
#pragma unroll
      for (int df = 0; df < 8; df++) {
        s8v vf = *(const s8v*)(vbase + (size_t)(df * 16 + lo) * 2048 + kv0 + ks2 * 32);
        Oa[df] = __builtin_amdgcn_mfma_f32_16x16x32_bf16(pa, vf, Oa[df], 0, 0, 0);
      }
    }
  }

#pragma unroll
  for (int j = 0; j < 4; j++) {
    float inv = 1.0f / l_r[j];
    u16* orow = O + (size_t)(b * 2048 + qb + hi * 4 + j) * 2048 + h * 128;
#pragma unroll
    for (int df = 0; df < 8; df++) orow[df * 16 + lo] = f2bf(Oa[df][j] * inv);
  }
}

// =====================================================================
extern "C" void kernel_launch(void* const* d_in, const int* in_sizes, int n_in,
                              void* d_out, int out_size, void* d_ws, size_t ws_size,
                              hipStream_t stream) {
  (void)in_sizes; (void)n_in; (void)out_size; (void)ws_size;
  const float* x     = (const float*)d_in[0];
  const float* freqs = (const float*)d_in[2];
  const float* W_dq  = (const float*)d_in[4];
  const float* W_uq  = (const float*)d_in[5];
  const float* W_dkv = (const float*)d_in[6];
  const float* W_uk  = (const float*)d_in[7];
  const float* W_uv  = (const float*)d_in[8];
  const float* W_qr  = (const float*)d_in[9];
  const float* W_kr  = (const float*)d_in[10];
  const float* W_o   = (const float*)d_in[11];
  const float* g_q   = (const float*)d_in[12];
  const float* g_kv  = (const float*)d_in[13];
  float* out = (float*)d_out;

  const int M = 8192;  // B*T
  char* w = (char*)d_ws;
  auto alloc = [&](size_t n) { char* p = w; w += (n + 255) & ~(size_t)255; return p; };

  u16* xb     = (u16*)alloc((size_t)M * 2048 * 2);  // also reused as vtmp and aout
  u16* wdq    = (u16*)alloc((size_t)1536 * 2048 * 2);
  u16* wuq    = (u16*)alloc((size_t)2048 * 1536 * 2);
  u16* wdkv   = (u16*)alloc((size_t)512 * 2048 * 2);
  u16* wuk    = (u16*)alloc((size_t)2048 * 512 * 2);
  u16* wuv    = (u16*)alloc((size_t)2048 * 512 * 2);
  u16* wqr    = (u16*)alloc((size_t)1024 * 1536 * 2);
  u16* wkr    = (u16*)alloc((size_t)64 * 2048 * 2);
  u16* wo     = (u16*)alloc((size_t)2048 * 2048 * 2);
  u16* q_c    = (u16*)alloc((size_t)M * 1536 * 2);
  u16* kv_c   = (u16*)alloc((size_t)M * 512 * 2);
  u16* qr_raw = (u16*)alloc((size_t)M * 1024 * 2);
  u16* kr_raw = (u16*)alloc((size_t)M * 64 * 2);
  u16* qbuf   = (u16*)alloc((size_t)M * 3072 * 2);
  u16* kbuf   = (u16*)alloc((size_t)M * 3072 * 2);
  u16* vt     = (u16*)alloc((size_t)M * 2048 * 2);
  // lifetime-disjoint aliases of xb (xb dead after W_kr GEMM):
  u16* vtmp = xb;
  u16* aout = xb;

  // ---- preamble: bf16 conversion + weight transposes ----
  k_f32_to_bf16<<<M * 2048 / 8 / 256, 256, 0, stream>>>(x, xb, M * 2048 / 8);
  k_transpose_bf16<<<dim3(1536 / 32, 2048 / 32), 256, 0, stream>>>(W_dq, wdq, 2048, 1536);
  k_transpose_bf16<<<dim3(2048 / 32, 1536 / 32), 256, 0, stream>>>(W_uq, wuq, 1536, 2048);
  k_transpose_bf16<<<dim3(512 / 32, 2048 / 32), 256, 0, stream>>>(W_dkv, wdkv, 2048, 512);
  k_transpose_bf16<<<dim3(2048 / 32, 512 / 32), 256, 0, stream>>>(W_uk, wuk, 512, 2048);
  k_transpose_bf16<<<dim3(2048 / 32, 512 / 32), 256, 0, stream>>>(W_uv, wuv, 512, 2048);
  k_transpose_bf16<<<dim3(1024 / 32, 1536 / 32), 256, 0, stream>>>(W_qr, wqr, 1536, 1024);
  k_transpose_bf16<<<dim3(64 / 32, 2048 / 32), 256, 0, stream>>>(W_kr, wkr, 2048, 64);
  k_transpose_bf16<<<dim3(2048 / 32, 2048 / 32), 256, 0, stream>>>(W_o, wo, 2048, 2048);

  // ---- latent projections + RMSNorm ----
  k_gemm_bt<128, 128, 2, 2, u16, false><<<(M / 128) * (1536 / 128), 256, 0, stream>>>(
      xb, wdq, q_c, M, 1536, 2048, 1536);
  k_rmsnorm<<<M, 256, 0, stream>>>(q_c, g_q, 1536);
  k_gemm_bt<128, 128, 2, 2, u16, false><<<(M / 128) * (512 / 128), 256, 0, stream>>>(
      xb, wdkv, kv_c, M, 512, 2048, 512);
  k_rmsnorm<<<M, 256, 0, stream>>>(kv_c, g_kv, 512);

  // ---- Q: nope (remapped into 192-stride) + rope ----
  k_gemm_bt<128, 128, 2, 2, u16, true><<<(M / 128) * (2048 / 128), 256, 0, stream>>>(
      q_c, wuq, qbuf, M, 2048, 1536, 3072);
  k_gemm_bt<128, 128, 2, 2, u16, false><<<(M / 128) * (1024 / 128), 256, 0, stream>>>(
      q_c, wqr, qr_raw, M, 1024, 1536, 1024);
  k_rope_q<<<M * 16 / 256, 256, 0, stream>>>(qr_raw, freqs, qbuf);

  // ---- K: nope + broadcast rope ----
  k_gemm_bt<128, 128, 2, 2, u16, true><<<(M / 128) * (2048 / 128), 256, 0, stream>>>(
      kv_c, wuk, kbuf, M, 2048, 512, 3072);
  k_gemm_bt<128, 64, 4, 1, u16, false><<<(M / 128) * (64 / 64), 256, 0, stream>>>(
      xb, wkr, kr_raw, M, 64, 2048, 64);
  k_rope_k<<<M * 16 / 256, 256, 0, stream>>>(kr_raw, freqs, kbuf);

  // ---- V + transpose to (B,H,128,T) ----  (xb no longer needed past here)
  k_gemm_bt<128, 128, 2, 2, u16, false><<<(M / 128) * (2048 / 128), 256, 0, stream>>>(
      kv_c, wuv, vtmp, M, 2048, 512, 2048);
  k_transpose_v<<<dim3(M / 64, 2048 / 64), 256, 0, stream>>>(vtmp, vt);

  // ---- attention ----
  k_attn<<<4 * 16 * 32, 256, 0, stream>>>(qbuf, kbuf, vt, aout);

  // ---- output projection (f32 out) ----
  k_gemm_bt<128, 128, 2, 2, float, false><<<(M / 128) * (2048 / 128), 256, 0, stream>>>(
      aout, wo, out, M, 2048, 2048, 2048);
}

// Round 2
// 838.956 us; speedup vs baseline: 2.2807x; 2.2807x over previous
//
#include <hip/hip_runtime.h>
#include <cstdint>
#include <cstddef>

typedef unsigned short u16;
typedef __attribute__((ext_vector_type(8))) short s8v;   // 8 x bf16 (4 VGPRs) MFMA A/B frag
typedef __attribute__((ext_vector_type(4))) float f4v;   // MFMA C/D frag

__device__ __forceinline__ float bf2f(u16 u) {
  union { unsigned u; float f; } v; v.u = ((unsigned)u) << 16; return v.f;
}
__device__ __forceinline__ u16 f2bf(float f) {
  union { float f; unsigned u; } v; v.f = f;
  unsigned r = v.u + 0x7FFFu + ((v.u >> 16) & 1u);   // RNE
  return (u16)(r >> 16);
}

// async global->LDS, 16B per lane. LDS dest must be wave-uniform base; HW adds lane*16.
__device__ __forceinline__ void async16(u16* lds, const u16* g) {
  __builtin_amdgcn_global_load_lds((const __attribute__((address_space(1))) void*)g,
                                   (__attribute__((address_space(3))) void*)lds,
                                   16, 0, 0);
}

// ---------------- elementwise f32 -> bf16 ----------------
__global__ __launch_bounds__(256) void k_f32_to_bf16(const float* __restrict__ in,
                                                     u16* __restrict__ out, int n8) {
  int i = blockIdx.x * 256 + threadIdx.x;
  if (i >= n8) return;
  const float4* p = (const float4*)(in + (size_t)i * 8);
  float4 a = p[0], b = p[1];
  s8v ov;
  ov[0] = (short)f2bf(a.x); ov[1] = (short)f2bf(a.y);
  ov[2] = (short)f2bf(a.z); ov[3] = (short)f2bf(a.w);
  ov[4] = (short)f2bf(b.x); ov[5] = (short)f2bf(b.y);
  ov[6] = (short)f2bf(b.z); ov[7] = (short)f2bf(b.w);
  *(s8v*)(out + (size_t)i * 8) = ov;
}

// ---------------- W (K,N) f32 -> Wt (N,K) bf16 ----------------
__global__ __launch_bounds__(256) void k_transpose_bf16(const float* __restrict__ W,
                                                        u16* __restrict__ Wt, int K, int N) {
  __shared__ float tile[32][33];
  int n0 = blockIdx.x * 32, k0 = blockIdx.y * 32;
  int tx = threadIdx.x & 31, ty = threadIdx.x >> 5;  // ty 0..7
#pragma unroll
  for (int i = 0; i < 32; i += 8)
    tile[ty + i][tx] = W[(size_t)(k0 + ty + i) * N + n0 + tx];
  __syncthreads();
#pragma unroll
  for (int i = 0; i < 32; i += 8)
    Wt[(size_t)(n0 + ty + i) * K + k0 + tx] = f2bf(tile[tx][ty + i]);
}

// ---------------- GEMM: C(M,N) = A(M,K) * Bt(N,K)^T, bf16 in, bf16/f32 out ----------
template <int BM, int BN, int WVM, int WVN, typename OutT, bool REMAP>
__global__ __launch_bounds__(256, 2) void k_gemm_bt(const u16* __restrict__ A,
                                                    const u16* __restrict__ Bt,
                                                    OutT* __restrict__ C,
                                                    int M, int N, int K, int ldc) {
  constexpr int FM = BM / WVM / 16, FN = BN / WVN / 16;
  __shared__ __align__(16) u16 As[BM * 32];
  __shared__ __align__(16) u16 Bs[BN * 32];
  const int tid = threadIdx.x, wv = tid >> 6, ln = tid & 63;
  const int lo = ln & 15, hi = ln >> 4;
  const int wr = wv / WVN, wc = wv % WVN;

  int nwg = gridDim.x, bid = blockIdx.x;
  int s = (bid & 7) * (nwg >> 3) + (bid >> 3);  // XCD swizzle (nwg % 8 == 0 for all uses)
  int gm = M / BM;
  int m0 = (s % gm) * BM, n0 = (s / gm) * BN;

  f4v acc[FM][FN] = {};

  for (int k0 = 0; k0 < K; k0 += 32) {
    __syncthreads();  // protect LDS from previous iteration's readers
#pragma unroll
    for (int i = 0; i < BM / 64; i++) {
      int r = i * 64 + wv * 16 + (ln >> 2);
      async16(&As[(i * 64 + wv * 16) * 32],
              A + (size_t)(m0 + r) * K + k0 + (ln & 3) * 8);
    }
#pragma unroll
    for (int i = 0; i < BN / 64; i++) {
      int r = i * 64 + wv * 16 + (ln >> 2);
      async16(&Bs[(i * 64 + wv * 16) * 32],
              Bt + (size_t)(n0 + r) * K + k0 + (ln & 3) * 8);
    }
    __syncthreads();  // drains vmcnt(0): staged data visible

    s8v af[FM], bf[FN];
#pragma unroll
    for (int m = 0; m < FM; m++)
      af[m] = *(const s8v*)&As[(wr * FM * 16 + m * 16 + lo) * 32 + hi * 8];
#pragma unroll
    for (int n = 0; n < FN; n++)
      bf[n] = *(const s8v*)&Bs[(wc * FN * 16 + n * 16 + lo) * 32 + hi * 8];
#pragma unroll
    for (int m = 0; m < FM; m++)
#pragma unroll
      for (int n = 0; n < FN; n++)
        acc[m][n] = __builtin_amdgcn_mfma_f32_16x16x32_bf16(af[m], bf[n], acc[m][n], 0, 0, 0);
  }

#pragma unroll
  for (int m = 0; m < FM; m++)
#pragma unroll
    for (int n = 0; n < FN; n++)
#pragma unroll
      for (int j = 0; j < 4; j++) {
        int row = m0 + wr * FM * 16 + m * 16 + hi * 4 + j;
        int col = n0 + wc * FN * 16 + n * 16 + lo;
        int dc = REMAP ? ((col >> 7) * 192 + (col & 127)) : col;
        float v = acc[m][n][j];
        if constexpr (sizeof(OutT) == 2)
          C[(size_t)row * ldc + dc] = (OutT)f2bf(v);
        else
          C[(size_t)row * ldc + dc] = (OutT)v;
      }
}

// ---------------- in-place RMSNorm over rows of bf16 (C <= 2048) ----------------
__global__ __launch_bounds__(256) void k_rmsnorm(u16* __restrict__ buf,
                                                 const float* __restrict__ g, int C) {
  int row = blockIdx.x;
  u16* p = buf + (size_t)row * C;
  int tid = threadIdx.x;
  bool act = tid * 8 < C;
  float x[8];
  float ss = 0.f;
  if (act) {
    s8v v = *(const s8v*)(p + tid * 8);
#pragma unroll
    for (int i = 0; i < 8; i++) { float xi = bf2f((u16)v[i]); x[i] = xi; ss += xi * xi; }
  }
#pragma unroll
  for (int off = 1; off < 64; off <<= 1) ss += __shfl_xor(ss, off);
  __shared__ float red[4];
  if ((tid & 63) == 0) red[tid >> 6] = ss;
  __syncthreads();
  float sc = rsqrtf((red[0] + red[1] + red[2] + red[3]) / (float)C + 1e-6f);
  if (act) {
    s8v ov;
#pragma unroll
    for (int i = 0; i < 8; i++) ov[i] = (short)f2bf(x[i] * sc * g[tid * 8 + i]);
    *(s8v*)(p + tid * 8) = ov;
  }
}

// ---------------- RoPE on q_rope, scatter into qbuf[:, h*192+128 ..] ----------------
__global__ __launch_bounds__(256) void k_rope_q(const u16* __restrict__ qr,
                                                const float* __restrict__ freqs,
                                                u16* __restrict__ qbuf) {
  int idx = blockIdx.x * 256 + threadIdx.x;  // (r,h)
  int r = idx >> 4, h = idx & 15;
  int t = r & 2047;
  const u16* src = qr + (size_t)r * 1024 + h * 64;
  u16* dst = qbuf + (size_t)r * 3072 + h * 192 + 128;
  const float* fc = freqs + (size_t)t * 64;
  u16 in[64], out[64];
#pragma unroll
  for (int c = 0; c < 8; c++) {
    s8v vv = *(const s8v*)(src + c * 8);
#pragma unroll
    for (int e = 0; e < 8; e++) in[c * 8 + e] = (u16)vv[e];
  }
#pragma unroll
  for (int i = 0; i < 32; i++) {
    float x1 = bf2f(in[2 * i]), x2 = bf2f(in[2 * i + 1]);
    float co = fc[2 * i], si = fc[2 * i + 1];
    out[2 * i] = f2bf(x1 * co - x2 * si);
    out[2 * i + 1] = f2bf(x1 * si + x2 * co);
  }
#pragma unroll
  for (int c = 0; c < 8; c++) {
    s8v ov;
#pragma unroll
    for (int e = 0; e < 8; e++) ov[e] = (short)out[c * 8 + e];
    *(s8v*)(dst + c * 8) = ov;
  }
}

// ---------------- RoPE on k_rope (shared across heads), broadcast into kbuf ----------
__global__ __launch_bounds__(256) void k_rope_k(const u16* __restrict__ kr,
                                                const float* __restrict__ freqs,
                                                u16* __restrict__ kbuf) {
  int idx = blockIdx.x * 256 + threadIdx.x;  // (r,h)
  int r = idx >> 4, h = idx & 15;
  int t = r & 2047;
  const u16* src = kr + (size_t)r * 64;
  u16* dst = kbuf + (size_t)r * 3072 + h * 192 + 128;
  const float* fc = freqs + (size_t)t * 64;
  u16 in[64], out[64];
#pragma unroll
  for (int c = 0; c < 8; c++) {
    s8v vv = *(const s8v*)(src + c * 8);
#pragma unroll
    for (int e = 0; e < 8; e++) in[c * 8 + e] = (u16)vv[e];
  }
#pragma unroll
  for (int i = 0; i < 32; i++) {
    float x1 = bf2f(in[2 * i]), x2 = bf2f(in[2 * i + 1]);
    float co = fc[2 * i], si = fc[2 * i + 1];
    out[2 * i] = f2bf(x1 * co - x2 * si);
    out[2 * i + 1] = f2bf(x1 * si + x2 * co);
  }
#pragma unroll
  for (int c = 0; c < 8; c++) {
    s8v ov;
#pragma unroll
    for (int e = 0; e < 8; e++) ov[e] = (short)out[c * 8 + e];
    *(s8v*)(dst + c * 8) = ov;
  }
}

// ---------------- V (token, h*128+d) -> Vt (B,H,128,T) ----------------
__global__ __launch_bounds__(256) void k_transpose_v(const u16* __restrict__ vtmp,
                                                     u16* __restrict__ vt) {
  __shared__ __align__(16) u16 tile[64][72];
  int r0 = blockIdx.x * 64, c0 = blockIdx.y * 64;
  int b = r0 >> 11, t0 = r0 & 2047;
  int h = c0 >> 7, d0 = c0 & 127;
  int tid = threadIdx.x;
  int ci = (tid & 7) * 8, ri = tid >> 3;  // ri 0..31
#pragma unroll
  for (int i = 0; i < 2; i++)
    *(s8v*)&tile[ri + 32 * i][ci] =
        *(const s8v*)(vtmp + (size_t)(r0 + ri + 32 * i) * 2048 + c0 + ci);
  __syncthreads();
  int tx = tid & 7, rr = tid >> 3;
#pragma unroll
  for (int i = 0; i < 2; i++) {
    int dr = rr + 32 * i;
    s8v ov;
#pragma unroll
    for (int e = 0; e < 8; e++) ov[e] = (short)tile[tx * 8 + e][dr];
    *(s8v*)(vt + (size_t)((b * 16 + h) * 128 + d0 + dr) * 2048 + t0 + tx * 8) = ov;
  }
}

// ---------------- causal flash attention, LDS-staged K/V ----------------
// Q,K: (B*T, H, 192) bf16 (nope|rope). V: (B,H,128,T) bf16. O: (B*T, H*128) bf16.
// Block = 4 waves, 64 q-rows (wave w owns rows qb..qb+15). KV tile = 64.
// K-tile (64x192) and V-tile (128x64) staged in LDS once per tile, shared by all
// waves; reg-staged with XOR chunk swizzle (chunk ^= row&7) on write AND read so
// the stride-384B / stride-128B ds_read_b128 fragment reads are ~2-way (free).
// T14: next tile's global loads issue before compute; ds_write after barrier.
__global__ __launch_bounds__(256, 3) void k_attn(const u16* __restrict__ Q,
                                                 const u16* __restrict__ K,
                                                 const u16* __restrict__ V,
                                                 u16* __restrict__ O) {
  __shared__ __align__(16) u16 Ks[64 * 192];      // 24.6 KB, row stride 384 B
  __shared__ __align__(16) u16 Vs[128 * 64];      // 16.4 KB, row stride 128 B
  __shared__ __align__(16) u16 p_lds[4][16 * 88]; // 11.3 KB
  int bid = blockIdx.x;
  // XCD-chunked remap (2048 = 8 XCD x 256) + long-tiles-first for causal balance
  int lw = (bid & 7) * 256 + (bid >> 3);
  int qt = 31 - (lw & 31), h = (lw >> 5) & 15, b = lw >> 9;
  int tid = threadIdx.x, wv = tid >> 6, ln = tid & 63;
  int lo = ln & 15, hi = ln >> 4, lo7 = lo & 7;
  int qb = qt * 64 + wv * 16;  // q start within sequence (0..2032)

  const u16* qptr = Q + (size_t)(b * 2048 + qb + lo) * 3072 + h * 192 + hi * 8;
  s8v qf[6];
#pragma unroll
  for (int ks = 0; ks < 6; ks++) qf[ks] = *(const s8v*)(qptr + ks * 32);

  f4v Oa[8] = {};
  float m_r[4], l_r[4];
#pragma unroll
  for (int j = 0; j < 4; j++) { m_r[j] = -3e38f; l_r[j] = 0.f; }
  const float scale = 0.07216878364870323f;  // 1/sqrt(192)

  // --- per-thread staging slots (fixed across tiles) ---
  const u16* kg = K + (size_t)(b * 2048) * 3072 + h * 192;       // + (kv0+r)*3072 + c*8
  const u16* vg = V + (size_t)((b * 16 + h) * 128) * 2048;       // + r*2048 + kv0 + c*8
  int kgo[6], klo[6];  // K: 64 rows x 24 chunks(16B) = 1536 chunks / 256 thr = 6
#pragma unroll
  for (int i = 0; i < 6; i++) {
    int id = i * 256 + tid, r = id / 24, c = id % 24;
    kgo[i] = r * 3072 + c * 8;
    klo[i] = r * 192 + (c ^ (r & 7)) * 8;
  }
  int vgo[4], vlo[4];  // V: 128 rows x 8 chunks = 1024 chunks / 256 thr = 4
#pragma unroll
  for (int i = 0; i < 4; i++) {
    int id = i * 256 + tid, r = id >> 3, c = id & 7;
    vgo[i] = r * 2048 + c * 8;
    vlo[i] = r * 64 + (c ^ (r & 7)) * 8;
  }

  u16* pl = p_lds[wv];
  int last = (qb + 15) >> 6;
  s8v kreg[6], vreg[4];

  // prologue: stage tile 0
#pragma unroll
  for (int i = 0; i < 6; i++) kreg[i] = *(const s8v*)(kg + kgo[i]);
#pragma unroll
  for (int i = 0; i < 4; i++) vreg[i] = *(const s8v*)(vg + vgo[i]);
#pragma unroll
  for (int i = 0; i < 6; i++) *(s8v*)&Ks[klo[i]] = kreg[i];
#pragma unroll
  for (int i = 0; i < 4; i++) *(s8v*)&Vs[vlo[i]] = vreg[i];
  __syncthreads();

  for (int t = 0; t <= last; t++) {
    int kv0 = t * 64;
    // T14: issue next tile's global loads now; latency hides under compute
    if (t < last) {
      size_t ksh = (size_t)(kv0 + 64) * 3072;
#pragma unroll
      for (int i = 0; i < 6; i++) kreg[i] = *(const s8v*)(kg + ksh + kgo[i]);
#pragma unroll
      for (int i = 0; i < 4; i++) vreg[i] = *(const s8v*)(vg + (kv0 + 64) + vgo[i]);
    }

    // ---- QK^T from swizzled LDS ----
    f4v S[4] = {};
#pragma unroll
    for (int ks = 0; ks < 6; ks++)
#pragma unroll
      for (int nf = 0; nf < 4; nf++) {
        s8v kf = *(const s8v*)&Ks[(nf * 16 + lo) * 192 + (((ks * 4 + hi) ^ lo7) * 8)];
        S[nf] = __builtin_amdgcn_mfma_f32_16x16x32_bf16(qf[ks], kf, S[nf], 0, 0, 0);
      }

    // ---- online softmax ----
    float p[4][4], tmax[4];
#pragma unroll
    for (int j = 0; j < 4; j++) tmax[j] = -3e38f;
    bool diag = (t == last);
#pragma unroll
    for (int nf = 0; nf < 4; nf++)
#pragma unroll
      for (int j = 0; j < 4; j++) {
        float sv = S[nf][j] * scale;
        if (diag && (kv0 + nf * 16 + lo > qb + hi * 4 + j)) sv = -3e38f;
        p[nf][j] = sv;
        tmax[j] = fmaxf(tmax[j], sv);
      }
#pragma unroll
    for (int off = 1; off < 16; off <<= 1)
#pragma unroll
      for (int j = 0; j < 4; j++) tmax[j] = fmaxf(tmax[j], __shfl_xor(tmax[j], off));
    float fj[4], ts[4];
#pragma unroll
    for (int j = 0; j < 4; j++) {
      float nm = fmaxf(m_r[j], tmax[j]);
      fj[j] = __expf(m_r[j] - nm);
      m_r[j] = nm;
      ts[j] = 0.f;
    }
#pragma unroll
    for (int nf = 0; nf < 4; nf++)
#pragma unroll
      for (int j = 0; j < 4; j++) {
        float pv = __expf(p[nf][j] - m_r[j]);
        p[nf][j] = pv;
        ts[j] += pv;
      }
#pragma unroll
    for (int off = 1; off < 16; off <<= 1)
#pragma unroll
      for (int j = 0; j < 4; j++) ts[j] += __shfl_xor(ts[j], off);
#pragma unroll
    for (int j = 0; j < 4; j++) l_r[j] = l_r[j] * fj[j] + ts[j];
#pragma unroll
    for (int df = 0; df < 8; df++)
#pragma unroll
      for (int j = 0; j < 4; j++) Oa[df][j] *= fj[j];

    // P (C-layout) -> per-wave LDS -> A-fragment layout
#pragma unroll
    for (int nf = 0; nf < 4; nf++)
#pragma unroll
      for (int j = 0; j < 4; j++)
        pl[(hi * 4 + j) * 88 + nf * 16 + lo] = f2bf(p[nf][j]);

    // ---- PV from swizzled LDS ----
#pragma unroll
    for (int ks2 = 0; ks2 < 2; ks2++) {
      s8v pa = *(const s8v*)&pl[lo * 88 + ks2 * 32 + hi * 8];
#pragma unroll
      for (int df = 0; df < 8; df++) {
        s8v vf = *(const s8v*)&Vs[(df * 16 + lo) * 64 + (((ks2 * 4 + hi) ^ lo7) * 8)];
        Oa[df] = __builtin_amdgcn_mfma_f32_16x16x32_bf16(pa, vf, Oa[df], 0, 0, 0);
      }
    }

    __syncthreads();  // all waves done reading tile t
    if (t < last) {
#pragma unroll
      for (int i = 0; i < 6; i++) *(s8v*)&Ks[klo[i]] = kreg[i];
#pragma unroll
      for (int i = 0; i < 4; i++) *(s8v*)&Vs[vlo[i]] = vreg[i];
      __syncthreads();  // tile t+1 visible
    }
  }

#pragma unroll
  for (int j = 0; j < 4; j++) {
    float inv = 1.0f / l_r[j];
    u16* orow = O + (size_t)(b * 2048 + qb + hi * 4 + j) * 2048 + h * 128;
#pragma unroll
    for (int df = 0; df < 8; df++) orow[df * 16 + lo] = f2bf(Oa[df][j] * inv);
  }
}

// =====================================================================
extern "C" void kernel_launch(void* const* d_in, const int* in_sizes, int n_in,
                              void* d_out, int out_size, void* d_ws, size_t ws_size,
                              hipStream_t stream) {
  (void)in_sizes; (void)n_in; (void)out_size; (void)ws_size;
  const float* x     = (const float*)d_in[0];
  const float* freqs = (const float*)d_in[2];
  const float* W_dq  = (const float*)d_in[4];
  const float* W_uq  = (const float*)d_in[5];
  const float* W_dkv = (const float*)d_in[6];
  const float* W_uk  = (const float*)d_in[7];
  const float* W_uv  = (const float*)d_in[8];
  const float* W_qr  = (const float*)d_in[9];
  const float* W_kr  = (const float*)d_in[10];
  const float* W_o   = (const float*)d_in[11];
  const float* g_q   = (const float*)d_in[12];
  const float* g_kv  = (const float*)d_in[13];
  float* out = (float*)d_out;

  const int M = 8192;  // B*T
  char* w = (char*)d_ws;
  auto alloc = [&](size_t n) { char* p = w; w += (n + 255) & ~(size_t)255; return p; };

  u16* xb     = (u16*)alloc((size_t)M * 2048 * 2);  // also reused as vtmp and aout
  u16* wdq    = (u16*)alloc((size_t)1536 * 2048 * 2);
  u16* wuq    = (u16*)alloc((size_t)2048 * 1536 * 2);
  u16* wdkv   = (u16*)alloc((size_t)512 * 2048 * 2);
  u16* wuk    = (u16*)alloc((size_t)2048 * 512 * 2);
  u16* wuv    = (u16*)alloc((size_t)2048 * 512 * 2);
  u16* wqr    = (u16*)alloc((size_t)1024 * 1536 * 2);
  u16* wkr    = (u16*)alloc((size_t)64 * 2048 * 2);
  u16* wo     = (u16*)alloc((size_t)2048 * 2048 * 2);
  u16* q_c    = (u16*)alloc((size_t)M * 1536 * 2);
  u16* kv_c   = (u16*)alloc((size_t)M * 512 * 2);
  u16* qr_raw = (u16*)alloc((size_t)M * 1024 * 2);
  u16* kr_raw = (u16*)alloc((size_t)M * 64 * 2);
  u16* qbuf   = (u16*)alloc((size_t)M * 3072 * 2);
  u16* kbuf   = (u16*)alloc((size_t)M * 3072 * 2);
  u16* vt     = (u16*)alloc((size_t)M * 2048 * 2);
  // lifetime-disjoint aliases of xb (xb dead after W_kr GEMM):
  u16* vtmp = xb;
  u16* aout = xb;

  // ---- preamble: bf16 conversion + weight transposes ----
  k_f32_to_bf16<<<M * 2048 / 8 / 256, 256, 0, stream>>>(x, xb, M * 2048 / 8);
  k_transpose_bf16<<<dim3(1536 / 32, 2048 / 32), 256, 0, stream>>>(W_dq, wdq, 2048, 1536);
  k_transpose_bf16<<<dim3(2048 / 32, 1536 / 32), 256, 0, stream>>>(W_uq, wuq, 1536, 2048);
  k_transpose_bf16<<<dim3(512 / 32, 2048 / 32), 256, 0, stream>>>(W_dkv, wdkv, 2048, 512);
  k_transpose_bf16<<<dim3(2048 / 32, 512 / 32), 256, 0, stream>>>(W_uk, wuk, 512, 2048);
  k_transpose_bf16<<<dim3(2048 / 32, 512 / 32), 256, 0, stream>>>(W_uv, wuv, 512, 2048);
  k_transpose_bf16<<<dim3(1024 / 32, 1536 / 32), 256, 0, stream>>>(W_qr, wqr, 1536, 1024);
  k_transpose_bf16<<<dim3(64 / 32, 2048 / 32), 256, 0, stream>>>(W_kr, wkr, 2048, 64);
  k_transpose_bf16<<<dim3(2048 / 32, 2048 / 32), 256, 0, stream>>>(W_o, wo, 2048, 2048);

  // ---- latent projections + RMSNorm ----
  k_gemm_bt<128, 128, 2, 2, u16, false><<<(M / 128) * (1536 / 128), 256, 0, stream>>>(
      xb, wdq, q_c, M, 1536, 2048, 1536);
  k_rmsnorm<<<M, 256, 0, stream>>>(q_c, g_q, 1536);
  k_gemm_bt<128, 128, 2, 2, u16, false><<<(M / 128) * (512 / 128), 256, 0, stream>>>(
      xb, wdkv, kv_c, M, 512, 2048, 512);
  k_rmsnorm<<<M, 256, 0, stream>>>(kv_c, g_kv, 512);

  // ---- Q: nope (remapped into 192-stride) + rope ----
  k_gemm_bt<128, 128, 2, 2, u16, true><<<(M / 128) * (2048 / 128), 256, 0, stream>>>(
      q_c, wuq, qbuf, M, 2048, 1536, 3072);
  k_gemm_bt<128, 128, 2, 2, u16, false><<<(M / 128) * (1024 / 128), 256, 0, stream>>>(
      q_c, wqr, qr_raw, M, 1024, 1536, 1024);
  k_rope_q<<<M * 16 / 256, 256, 0, stream>>>(qr_raw, freqs, qbuf);

  // ---- K: nope + broadcast rope ----
  k_gemm_bt<128, 128, 2, 2, u16, true><<<(M / 128) * (2048 / 128), 256, 0, stream>>>(
      kv_c, wuk, kbuf, M, 2048, 512, 3072);
  k_gemm_bt<128, 64, 4, 1, u16, false><<<(M / 128) * (64 / 64), 256, 0, stream>>>(
      xb, wkr, kr_raw, M, 64, 2048, 64);
  k_rope_k<<<M * 16 / 256, 256, 0, stream>>>(kr_raw, freqs, kbuf);

  // ---- V + transpose to (B,H,128,T) ----  (xb no longer needed past here)
  k_gemm_bt<128, 128, 2, 2, u16, false><<<(M / 128) * (2048 / 128), 256, 0, stream>>>(
      kv_c, wuv, vtmp, M, 2048, 512, 2048);
  k_transpose_v<<<dim3(M / 64, 2048 / 64), 256, 0, stream>>>(vtmp, vt);

  // ---- attention ----
  k_attn<<<4 * 16 * 32, 256, 0, stream>>>(qbuf, kbuf, vt, aout);

  // ---- output projection (f32 out) ----
  k_gemm_bt<128, 128, 2, 2, float, false><<<(M / 128) * (2048 / 128), 256, 0, stream>>>(
      aout, wo, out, M, 2048, 2048, 2048);
}